// Round 19
// baseline (489.099 us; speedup 1.0000x reference)
//
#include <hip/hip_runtime.h>

typedef __bf16 bf16x8 __attribute__((ext_vector_type(8)));
typedef __bf16 bf16x4 __attribute__((ext_vector_type(4)));
typedef float f32x4 __attribute__((ext_vector_type(4)));

__device__ __forceinline__ f32x4 mfma16(bf16x8 a, bf16x8 b, f32x4 c) {
  return __builtin_amdgcn_mfma_f32_16x16x32_bf16(a, b, c, 0, 0, 0);
}

__device__ __forceinline__ void load_lds16(const void* g, void* l) {
  __builtin_amdgcn_global_load_lds(
      (const __attribute__((address_space(1))) void*)g,
      (__attribute__((address_space(3))) void*)l, 16, 0, 0);
}

// Bijective XCD chunk swizzle (m204).
template <int NWG>
__device__ __forceinline__ int xcd_swz(int orig) {
  constexpr int NX = 8;
  constexpr int q = NWG / NX;
  constexpr int r = NWG % NX;
  const int xcd = orig % NX;
  const int pos = orig / NX;
  if constexpr (r == 0) {
    return xcd * q + pos;
  } else {
    return (xcd < r ? xcd * (q + 1) : r * (q + 1) + (xcd - r) * q) + pos;
  }
}

// ---------------- merged prep: W transpose (gamma folded into Wq) + bias fold + LN stats ----------------
// bid [0,2304): W transpose tiles (z==0 rows scaled by gamma[k]).
// bid [2304,2307): bq2[n] = bq[n] + sum_k beta[k]*Wq[k][n].
// bid [2307,2307+16384): LN stats {mu, rsigma} per row of e.
__global__ __launch_bounds__(256) void prep_kernel(
    const float* __restrict__ Wq, const float* __restrict__ Wk,
    const float* __restrict__ Wv, const float* __restrict__ Wo,
    __bf16* __restrict__ WqT, __bf16* __restrict__ WkvT, __bf16* __restrict__ WoT,
    const float* __restrict__ e, const float* __restrict__ gam,
    const float* __restrict__ bet, float2* __restrict__ stats,
    const float* __restrict__ bq, float* __restrict__ bq2) {
  const int bid = blockIdx.x;
  const int t = threadIdx.x;
  if (bid < 2304) {
    __shared__ float tile[32][33];
    const int z = bid / 576;
    const int rr = bid % 576;
    const int bx = rr % 24, by = rr / 24;
    const float* W = (z == 0) ? Wq : (z == 1) ? Wk : (z == 2) ? Wv : Wo;
    __bf16* out = (z == 0) ? WqT : (z == 3) ? WoT : WkvT;
    const int rowOff = (z == 2) ? 768 : 0;
    const int tx = t & 31, ty = t >> 5;
    const int x = bx * 32 + tx;  // n (fast dim of W)
    const int y = by * 32 + ty;  // k
#pragma unroll
    for (int i = 0; i < 32; i += 8) {
      float v = W[(size_t)(y + i) * 768 + x];
      if (z == 0) v *= gam[y + i];       // fold gamma into Wq rows
      tile[ty + i][tx] = v;
    }
    __syncthreads();
    const int nx = by * 32 + tx;  // k (fast dim of WT)
    const int ny = bx * 32 + ty;  // n
#pragma unroll
    for (int i = 0; i < 32; i += 8)
      out[(size_t)(rowOff + ny + i) * 768 + nx] = (__bf16)tile[tx][ty + i];
  } else if (bid < 2307) {
    const int n = (bid - 2304) * 256 + t;
    float s = bq[n];
    for (int k = 0; k < 768; ++k) s += bet[k] * Wq[(size_t)k * 768 + n];
    bq2[n] = s;
  } else {
    const int lane = t & 63;
    const int wid = t >> 6;
    const size_t row = (size_t)(bid - 2307) * 4 + wid;
    const float* p = e + row * 768;
    float x[12];
    float sum = 0.f;
#pragma unroll
    for (int s = 0; s < 3; ++s) {
      f32x4 v = *(const f32x4*)(p + (s * 64 + lane) * 4);
#pragma unroll
      for (int q = 0; q < 4; ++q) { x[s * 4 + q] = v[q]; sum += v[q]; }
    }
#pragma unroll
    for (int d = 1; d < 64; d <<= 1) sum += __shfl_xor(sum, d);
    const float m = sum * (1.f / 768.f);
    float vs = 0.f;
#pragma unroll
    for (int q = 0; q < 12; ++q) { float d = x[q] - m; vs += d * d; }
#pragma unroll
    for (int d = 1; d < 64; d <<= 1) vs += __shfl_xor(vs, d);
    if (lane == 0) {
      float2 st;
      st.x = m;
      st.y = rsqrtf(vs * (1.f / 768.f) + 1e-5f);
      stats[row] = st;
    }
  }
}

enum { MODE_Q = 0, MODE_KV = 1, MODE_O = 2 };

// ---------------- fp32-A GEMM body (Q: fused LN normalize; KV: fused cast) ----------------
// A register-staged (fp32 global -> VGPR -> cvt -> ds_write, linear LDS dest,
// source-column swizzle); B via global_load_lds.  4-slot rings, depth-2.
// Per-step VMEM: loadA = LA ops (Q: 4 data + 2 stats = 6; KV: 4), stageB = 2.
// Entry waits: kt<2 none; 2..21 vmcnt(LA+2); 22 vmcnt(2); 23 vmcnt(0).
template <int MODE, int NC>
__device__ __forceinline__ void gemm_f32a_body(
    int wgid, __bf16* As, __bf16* Bs,
    const float* __restrict__ Afp, const float2* __restrict__ stats,
    const __bf16* __restrict__ WT,
    const float* __restrict__ bias0, const float* __restrict__ bias1,
    __bf16* __restrict__ dst0, __bf16* __restrict__ dst1) {
  constexpr int LA = (MODE == MODE_Q) ? 6 : 4;
  const int rowBase = (wgid / NC) * 256;
  const int colBase = (wgid % NC) * 256;
  const int t = threadIdx.x;
  const int lane = t & 63, wid = t >> 6;
  const int wm = wid >> 2, wn = wid & 3;            // 2x4 waves; wave tile 128x64
  const int lr = lane & 15, lg = lane >> 4;
  const int srow = t >> 2;                          // staging row 0..127 per pass
  const int skcol = ((t & 3) ^ (srow & 3)) * 8;     // XOR-swizzled source granule
  const int cg = lg ^ (lr & 3);                     // swizzled read granule
  f32x4 acc[8][4] = {};
  f32x4 ra0, ra1, rb0, rb1;                         // staged A fp32 (p=0,1)
  float2 st0, st1;

  auto loadA = [&](int kt) {
    const float* g0 = Afp + (size_t)(rowBase + srow) * 768 + kt * 32 + skcol;
    const float* g1 = Afp + (size_t)(rowBase + 128 + srow) * 768 + kt * 32 + skcol;
    ra0 = *(const f32x4*)g0;
    ra1 = *(const f32x4*)(g0 + 4);
    rb0 = *(const f32x4*)g1;
    rb1 = *(const f32x4*)(g1 + 4);
    if constexpr (MODE == MODE_Q) {
      st0 = stats[rowBase + srow];
      st1 = stats[rowBase + 128 + srow];
    }
  };
  auto writeA = [&](int kt) {
    const int slot = kt & 3;
    bf16x8 pk0, pk1;
#pragma unroll
    for (int j = 0; j < 4; ++j) {
      float v0 = ra0[j], v1 = ra1[j], w0 = rb0[j], w1 = rb1[j];
      if constexpr (MODE == MODE_Q) {
        v0 = (v0 - st0.x) * st0.y; v1 = (v1 - st0.x) * st0.y;
        w0 = (w0 - st1.x) * st1.y; w1 = (w1 - st1.x) * st1.y;
      }
      pk0[j] = (__bf16)v0; pk0[j + 4] = (__bf16)v1;
      pk1[j] = (__bf16)w0; pk1[j + 4] = (__bf16)w1;
    }
    *(bf16x8*)&As[slot * 8192 + t * 8] = pk0;
    *(bf16x8*)&As[slot * 8192 + 4096 + t * 8] = pk1;
  };
  auto stageB = [&](int kt) {
    const int slot = kt & 3;
#pragma unroll
    for (int p = 0; p < 2; ++p) {
      const int rowIn = p * 128 + srow;
      const __bf16* gb = WT + (size_t)(colBase + rowIn) * 768 + kt * 32 + skcol;
      load_lds16(gb, &Bs[slot * 8192 + p * 4096 + t * 8]);
    }
  };

  // prologue: B(0),B(1) in flight; A(0),A(1) loaded+written (full drains, 1x cost)
  stageB(0); stageB(1);
  loadA(0);
  asm volatile("s_waitcnt vmcnt(0)" ::: "memory");
  __builtin_amdgcn_sched_barrier(0);
  writeA(0);
  loadA(1);
  asm volatile("s_waitcnt vmcnt(0)" ::: "memory");
  __builtin_amdgcn_sched_barrier(0);
  writeA(1);
  loadA(2);                                    // LA ops in flight
  asm volatile("s_waitcnt lgkmcnt(0)" ::: "memory");
  __builtin_amdgcn_sched_barrier(0);

#pragma unroll
  for (int kt = 0; kt < 24; ++kt) {
    const int slot = kt & 3;
    // entry wait: B(kt) retired (issue-order derivation in header comment)
    if (kt >= 2 && kt <= 21) {
      asm volatile("s_waitcnt vmcnt(%0)" :: "i"(LA + 2) : "memory");
    } else if (kt == 22) {
      asm volatile("s_waitcnt vmcnt(2)" ::: "memory");
    } else if (kt == 23) {
      asm volatile("s_waitcnt vmcnt(0)" ::: "memory");
    }
    __builtin_amdgcn_sched_barrier(0);
    __builtin_amdgcn_s_barrier();   // tile kt ready (A written step kt-1, B landed)

    // ---- phase 0: write A(kt+2), issue loadA(kt+3), compute it 0..3 ----
    if (kt + 2 < 24) {
      if (kt == 0) {
        asm volatile("s_waitcnt vmcnt(0)" ::: "memory");
      } else {
        asm volatile("s_waitcnt vmcnt(2)" ::: "memory");   // A(kt+2) gloads retired
      }
      __builtin_amdgcn_sched_barrier(0);
      writeA(kt + 2);
    }
    if (kt + 3 < 24) loadA(kt + 3);
    bf16x8 b[4], a0[4];
#pragma unroll
    for (int it = 0; it < 4; ++it)
      a0[it] = *(const bf16x8*)&As[slot * 8192 + (wm * 128 + it * 16 + lr) * 32 + cg * 8];
#pragma unroll
    for (int jt = 0; jt < 4; ++jt)
      b[jt] = *(const bf16x8*)&Bs[slot * 8192 + (wn * 64 + jt * 16 + lr) * 32 + cg * 8];
    asm volatile("s_waitcnt lgkmcnt(0)" ::: "memory");
    __builtin_amdgcn_sched_barrier(0);
    __builtin_amdgcn_s_setprio(1);
#pragma unroll
    for (int it = 0; it < 4; ++it)
#pragma unroll
      for (int jt = 0; jt < 4; ++jt)
        acc[it][jt] = mfma16(a0[it], b[jt], acc[it][jt]);
    __builtin_amdgcn_s_setprio(0);
    __builtin_amdgcn_s_barrier();   // phase rotation

    // ---- phase 1: it 4..7, issue stageB(kt+2) ----
    bf16x8 a1[4];
#pragma unroll
    for (int it = 0; it < 4; ++it)
      a1[it] = *(const bf16x8*)&As[slot * 8192 + (wm * 128 + (it + 4) * 16 + lr) * 32 + cg * 8];
    if (kt + 2 < 24) stageB(kt + 2);
    asm volatile("s_waitcnt lgkmcnt(0)" ::: "memory");
    __builtin_amdgcn_sched_barrier(0);
    __builtin_amdgcn_s_setprio(1);
#pragma unroll
    for (int it = 0; it < 4; ++it)
#pragma unroll
      for (int jt = 0; jt < 4; ++jt)
        acc[it + 4][jt] = mfma16(a1[it], b[jt], acc[it + 4][jt]);
    __builtin_amdgcn_s_setprio(0);
    // next kt's entry [vmcnt; s_barrier] provides the closing barrier
  }

  // ---- epilogue ----
  const int roww = rowBase + wm * 128;
  const int colw = colBase + wn * 64;
#pragma unroll
  for (int it = 0; it < 8; ++it) {
#pragma unroll
    for (int jt = 0; jt < 4; ++jt) {
      const int c = colw + jt * 16 + lr;
#pragma unroll
      for (int rg = 0; rg < 4; ++rg) {
        const int r = roww + it * 16 + lg * 4 + rg;
        const float val = acc[it][jt][rg];
        if constexpr (MODE == MODE_Q) {
          dst0[((((size_t)(r >> 6)) * 12 + (c >> 6)) << 12) + ((r & 63) << 6) + (c & 63)] =
              (__bf16)(val + bias0[c]);
        } else {  // KV
          if (c < 768) {
            dst0[((((size_t)(r >> 6)) * 12 + (c >> 6)) << 12) + ((r & 63) << 6) + (c & 63)] =
                (__bf16)(val + bias0[c]);
          } else {
            const int c2 = c - 768;
            dst1[((((size_t)(r >> 6)) * 12 + (c2 >> 6)) << 12) + ((c2 & 63) << 6) + (r & 63)] =
                (__bf16)(val + bias1[c2]);
          }
        }
      }
    }
  }
}

// ---------------- bf16-A GEMM body (MODE_O, unchanged R12 structure) ----------------
template <int NC>
__device__ __forceinline__ void gemm_o_body(
    int wgid, __bf16* As, __bf16* Bs,
    const __bf16* __restrict__ A, const __bf16* __restrict__ WT,
    const float* __restrict__ bias0, const float* __restrict__ eres,
    float* __restrict__ outp) {
  const int rowBase = (wgid / NC) * 256;
  const int colBase = (wgid % NC) * 256;
  const int t = threadIdx.x;
  const int lane = t & 63, wid = t >> 6;
  const int wm = wid >> 2, wn = wid & 3;
  const int lr = lane & 15, lg = lane >> 4;
  const int srow = t >> 2;
  const int skcol = ((t & 3) ^ (srow & 3)) * 8;
  const int cg = lg ^ (lr & 3);
  f32x4 acc[8][4] = {};

  auto stageA = [&](int kt) {
    const int slot = kt & 3;
#pragma unroll
    for (int p = 0; p < 2; ++p) {
      const int rowIn = p * 128 + srow;
      const int r = rowBase + rowIn;
      const __bf16* ga = A + ((((size_t)(r >> 6)) * 12 + (kt >> 1)) << 12) + ((r & 63) << 6) +
                         (kt & 1) * 32 + skcol;
      load_lds16(ga, &As[slot * 8192 + p * 4096 + t * 8]);
    }
  };
  auto stageB = [&](int kt) {
    const int slot = kt & 3;
#pragma unroll
    for (int p = 0; p < 2; ++p) {
      const int rowIn = p * 128 + srow;
      const __bf16* gb = WT + (size_t)(colBase + rowIn) * 768 + kt * 32 + skcol;
      load_lds16(gb, &Bs[slot * 8192 + p * 4096 + t * 8]);
    }
  };

  stageA(0); stageB(0);
  stageA(1); stageB(1);
  stageA(2); stageB(2);

#pragma unroll
  for (int kt = 0; kt < 24; ++kt) {
    const int slot = kt & 3;
    if (kt <= 21) {
      asm volatile("s_waitcnt vmcnt(8)" ::: "memory");
    } else if (kt == 22) {
      asm volatile("s_waitcnt vmcnt(4)" ::: "memory");
    } else {
      asm volatile("s_waitcnt vmcnt(0)" ::: "memory");
    }
    __builtin_amdgcn_sched_barrier(0);
    __builtin_amdgcn_s_barrier();

    bf16x8 b[4], a0[4];
#pragma unroll
    for (int it = 0; it < 4; ++it)
      a0[it] = *(const bf16x8*)&As[slot * 8192 + (wm * 128 + it * 16 + lr) * 32 + cg * 8];
#pragma unroll
    for (int jt = 0; jt < 4; ++jt)
      b[jt] = *(const bf16x8*)&Bs[slot * 8192 + (wn * 64 + jt * 16 + lr) * 32 + cg * 8];
    if (kt + 3 < 24) stageA(kt + 3);
    asm volatile("s_waitcnt lgkmcnt(0)" ::: "memory");
    __builtin_amdgcn_sched_barrier(0);
    __builtin_amdgcn_s_setprio(1);
#pragma unroll
    for (int it = 0; it < 4; ++it)
#pragma unroll
      for (int jt = 0; jt < 4; ++jt)
        acc[it][jt] = mfma16(a0[it], b[jt], acc[it][jt]);
    __builtin_amdgcn_s_setprio(0);
    __builtin_amdgcn_s_barrier();

    bf16x8 a1[4];
#pragma unroll
    for (int it = 0; it < 4; ++it)
      a1[it] = *(const bf16x8*)&As[slot * 8192 + (wm * 128 + (it + 4) * 16 + lr) * 32 + cg * 8];
    if (kt + 3 < 24) stageB(kt + 3);
    asm volatile("s_waitcnt lgkmcnt(0)" ::: "memory");
    __builtin_amdgcn_sched_barrier(0);
    __builtin_amdgcn_s_setprio(1);
#pragma unroll
    for (int it = 0; it < 4; ++it)
#pragma unroll
      for (int jt = 0; jt < 4; ++jt)
        acc[it + 4][jt] = mfma16(a1[it], b[jt], acc[it + 4][jt]);
    __builtin_amdgcn_s_setprio(0);
  }

  const int roww = rowBase + wm * 128;
  const int colw = colBase + wn * 64;
#pragma unroll
  for (int it = 0; it < 8; ++it) {
#pragma unroll
    for (int jt = 0; jt < 4; ++jt) {
      const int c = colw + jt * 16 + lr;
#pragma unroll
      for (int rg = 0; rg < 4; ++rg) {
        const int r = roww + it * 16 + lg * 4 + rg;
        outp[(size_t)r * 768 + c] = acc[it][jt][rg] + bias0[c] + eres[(size_t)r * 768 + c];
      }
    }
  }
}

// merged Q + KV GEMM (single grid: soft boundaries)
__global__ __launch_bounds__(512) void gemm_qkv_kernel(
    const float* __restrict__ e, const float2* __restrict__ stats,
    const __bf16* __restrict__ WqT, const float* __restrict__ bq2,
    __bf16* __restrict__ q_ws,
    const float* __restrict__ h, const __bf16* __restrict__ WkvT,
    const float* __restrict__ bk, const float* __restrict__ bv,
    __bf16* __restrict__ k_ws, __bf16* __restrict__ v_ws) {
  __shared__ __bf16 As[4 * 8192];
  __shared__ __bf16 Bs[4 * 8192];
  const int bid = blockIdx.x;
  if (bid < 768) {
    gemm_f32a_body<MODE_Q, 3>(xcd_swz<768>(bid), As, Bs, e, stats, WqT, bq2,
                              nullptr, q_ws, nullptr);
  } else {
    gemm_f32a_body<MODE_KV, 6>(xcd_swz<384>(bid - 768), As, Bs, h, nullptr,
                               WkvT, bk, bv, k_ws, v_ws);
  }
}

__global__ __launch_bounds__(512) void gemm_o_kernel(
    const __bf16* __restrict__ o_ws, const __bf16* __restrict__ WoT,
    const float* __restrict__ bo, const float* __restrict__ e,
    float* __restrict__ outp) {
  __shared__ __bf16 As[4 * 8192];
  __shared__ __bf16 Bs[4 * 8192];
  gemm_o_body<3>(xcd_swz<768>(blockIdx.x), As, Bs, o_ws, WoT, bo, e, outp);
}

// ---------------- attention: block = (bc,h), 4 waves = 4 n's sharing K/V in LDS ----------------
__global__ __launch_bounds__(256) void attn_kernel(
    const __bf16* __restrict__ q, const __bf16* __restrict__ k,
    const __bf16* __restrict__ v, __bf16* __restrict__ o) {
  const int bh = blockIdx.x;           // bc*12 + h
  const int h = bh % 12;
  const int bc = bh / 12;
  const int t = threadIdx.x;
  const int wid = t >> 6, lane = t & 63;
  const int lr = lane & 15, lg = lane >> 4;
  __shared__ __bf16 kL[64][72];
  __shared__ __bf16 vL[64][72];        // v stored transposed [d][j]
  __shared__ __bf16 P[4][64][72];      // per-wave P slab

  {
    const __bf16* kp = k + ((size_t)bh << 12);
    const __bf16* vp = v + ((size_t)bh << 12);
    const int row = t >> 2, col = (t & 3) * 16;
    *(bf16x8*)&kL[row][col]     = *(const bf16x8*)(kp + row * 64 + col);
    *(bf16x8*)&kL[row][col + 8] = *(const bf16x8*)(kp + row * 64 + col + 8);
    *(bf16x8*)&vL[row][col]     = *(const bf16x8*)(vp + row * 64 + col);
    *(bf16x8*)&vL[row][col + 8] = *(const bf16x8*)(vp + row * 64 + col + 8);
  }
  const __bf16* qp = q + (((size_t)(bc * 4 + wid) * 12 + h) << 12);
  __bf16* op = o + (((size_t)(bc * 4 + wid) * 12 + h) << 12);
  bf16x8 qf[4][2];
#pragma unroll
  for (int it = 0; it < 4; ++it)
#pragma unroll
    for (int kc = 0; kc < 2; ++kc)
      qf[it][kc] = *(const bf16x8*)(qp + (it * 16 + lr) * 64 + kc * 32 + lg * 8);
  __syncthreads();

  // S^T = k @ q^T : lane holds S[i = it*16+lr][j = jt*16+lg*4+rg]
  f32x4 s[4][4] = {};
#pragma unroll
  for (int kc = 0; kc < 2; ++kc) {
    bf16x8 kf[4];
#pragma unroll
    for (int jt = 0; jt < 4; ++jt)
      kf[jt] = *(const bf16x8*)&kL[jt * 16 + lr][kc * 32 + lg * 8];
#pragma unroll
    for (int jt = 0; jt < 4; ++jt)
#pragma unroll
      for (int it = 0; it < 4; ++it)
        s[jt][it] = mfma16(kf[jt], qf[it][kc], s[jt][it]);
  }

  float recip[4];
#pragma unroll
  for (int it = 0; it < 4; ++it) {
    float m = -1e30f;
#pragma unroll
    for (int jt = 0; jt < 4; ++jt)
#pragma unroll
      for (int rg = 0; rg < 4; ++rg) m = fmaxf(m, s[jt][it][rg]);
    m = fmaxf(m, __shfl_xor(m, 16));
    m = fmaxf(m, __shfl_xor(m, 32));
    float sum = 0.f;
#pragma unroll
    for (int jt = 0; jt < 4; ++jt) {
      bf16x4 pk;
#pragma unroll
      for (int rg = 0; rg < 4; ++rg) {
        float p = __expf((s[jt][it][rg] - m) * 0.125f);
        sum += p;
        pk[rg] = (__bf16)p;
      }
      *(bf16x4*)&P[wid][it * 16 + lr][jt * 16 + lg * 4] = pk;
    }
    sum += __shfl_xor(sum, 16);
    sum += __shfl_xor(sum, 32);
    recip[it] = 1.f / sum;
  }
  // P is per-wave: no block barrier needed

  // o^T = vT @ P^T
  f32x4 oacc[4][4] = {};
#pragma unroll
  for (int kc = 0; kc < 2; ++kc) {
    bf16x8 vf[4], pf[4];
#pragma unroll
    for (int dt = 0; dt < 4; ++dt)
      vf[dt] = *(const bf16x8*)&vL[dt * 16 + lr][kc * 32 + lg * 8];
#pragma unroll
    for (int it = 0; it < 4; ++it)
      pf[it] = *(const bf16x8*)&P[wid][it * 16 + lr][kc * 32 + lg * 8];
#pragma unroll
    for (int dt = 0; dt < 4; ++dt)
#pragma unroll
      for (int it = 0; it < 4; ++it)
        oacc[dt][it] = mfma16(vf[dt], pf[it], oacc[dt][it]);
  }
#pragma unroll
  for (int it = 0; it < 4; ++it) {
    const float rc = recip[it];
#pragma unroll
    for (int dt = 0; dt < 4; ++dt) {
      bf16x4 pk;
#pragma unroll
      for (int rg = 0; rg < 4; ++rg) pk[rg] = (__bf16)(oacc[dt][it][rg] * rc);
      *(bf16x4*)(op + (size_t)(it * 16 + lr) * 64 + dt * 16 + lg * 4) = pk;
    }
  }
}

extern "C" void kernel_launch(void* const* d_in, const int* in_sizes, int n_in,
                              void* d_out, int out_size, void* d_ws, size_t ws_size,
                              hipStream_t stream) {
  const float* e  = (const float*)d_in[0];
  const float* h  = (const float*)d_in[1];
  const float* Wq = (const float*)d_in[2];
  const float* bq = (const float*)d_in[3];
  const float* Wk = (const float*)d_in[4];
  const float* bk = (const float*)d_in[5];
  const float* Wv = (const float*)d_in[6];
  const float* bv = (const float*)d_in[7];
  const float* Wo = (const float*)d_in[8];
  const float* bo = (const float*)d_in[9];
  const float* g  = (const float*)d_in[10];
  const float* b  = (const float*)d_in[11];
  float* outp = (float*)d_out;
  char* ws = (char*)d_ws;

  __bf16* WqT   = (__bf16*)(ws);                   // 1,179,648
  __bf16* WkvT  = (__bf16*)(ws + 1179648);         // 2,359,296
  __bf16* WoT   = (__bf16*)(ws + 3538944);         // 1,179,648 -> ends 4,718,592
  float2* stats = (float2*)(ws + 4718592);         // 524,288   -> ends 5,242,880
  float*  bq2   = (float*)(ws + 5242880);          // 3,072
  __bf16* k_ws  = (__bf16*)(ws + 8388608);         // 25,165,824
  __bf16* v_ws  = (__bf16*)(ws + 33554432);        // 25,165,824
  __bf16* q_ws  = (__bf16*)(ws + 58720256);        // 100,663,296 (o in-place)

  prep_kernel<<<2307 + 16384, 256, 0, stream>>>(
      Wq, Wk, Wv, Wo, WqT, WkvT, WoT, e, g, b, stats, bq, bq2);
  gemm_qkv_kernel<<<1152, 512, 0, stream>>>(
      e, stats, WqT, bq2, q_ws, h, WkvT, bk, bv, k_ws, v_ws);
  attn_kernel<<<3072, 256, 0, stream>>>(q_ws, k_ws, v_ws, q_ws);
  gemm_o_kernel<<<768, 512, 0, stream>>>(q_ws, WoT, bo, e, outp);
}

// Round 20
// 453.363 us; speedup vs baseline: 1.0788x; 1.0788x over previous
//
#include <hip/hip_runtime.h>

typedef __bf16 bf16x8 __attribute__((ext_vector_type(8)));
typedef __bf16 bf16x4 __attribute__((ext_vector_type(4)));
typedef float f32x4 __attribute__((ext_vector_type(4)));

__device__ __forceinline__ f32x4 mfma16(bf16x8 a, bf16x8 b, f32x4 c) {
  return __builtin_amdgcn_mfma_f32_16x16x32_bf16(a, b, c, 0, 0, 0);
}

__device__ __forceinline__ void load_lds16(const void* g, void* l) {
  __builtin_amdgcn_global_load_lds(
      (const __attribute__((address_space(1))) void*)g,
      (__attribute__((address_space(3))) void*)l, 16, 0, 0);
}

// Bijective XCD chunk swizzle (m204).
template <int NWG>
__device__ __forceinline__ int xcd_swz(int orig) {
  constexpr int NX = 8;
  constexpr int q = NWG / NX;
  constexpr int r = NWG % NX;
  const int xcd = orig % NX;
  const int pos = orig / NX;
  if constexpr (r == 0) {
    return xcd * q + pos;
  } else {
    return (xcd < r ? xcd * (q + 1) : r * (q + 1) + (xcd - r) * q) + pos;
  }
}

// ---------------- merged: weight transpose (fp32->bf16 WT) + LayerNorm + h cast ----------------
// blocks [0,2304): prep_w tiles; [2304, 2304+16384): ln rows; rest: h cast.
__global__ __launch_bounds__(256) void prep_ln_cast_kernel(
    const float* __restrict__ Wq, const float* __restrict__ Wk,
    const float* __restrict__ Wv, const float* __restrict__ Wo,
    __bf16* __restrict__ WqT, __bf16* __restrict__ WkvT, __bf16* __restrict__ WoT,
    const float* __restrict__ e, const float* __restrict__ gam,
    const float* __restrict__ bet, __bf16* __restrict__ en,
    const float* __restrict__ hin, __bf16* __restrict__ h_bf) {
  const int bid = blockIdx.x;
  const int t = threadIdx.x;
  if (bid < 2304) {
    __shared__ float tile[32][33];
    const int z = bid / 576;
    const int rr = bid % 576;
    const int bx = rr % 24, by = rr / 24;
    const float* W = (z == 0) ? Wq : (z == 1) ? Wk : (z == 2) ? Wv : Wo;
    __bf16* out = (z == 0) ? WqT : (z == 3) ? WoT : WkvT;
    const int rowOff = (z == 2) ? 768 : 0;
    const int tx = t & 31, ty = t >> 5;
    const int x = bx * 32 + tx;  // n (fast dim of W)
    const int y = by * 32 + ty;  // k
#pragma unroll
    for (int i = 0; i < 32; i += 8) tile[ty + i][tx] = W[(size_t)(y + i) * 768 + x];
    __syncthreads();
    const int nx = by * 32 + tx;  // k (fast dim of WT)
    const int ny = bx * 32 + ty;  // n
#pragma unroll
    for (int i = 0; i < 32; i += 8)
      out[(size_t)(rowOff + ny + i) * 768 + nx] = (__bf16)tile[tx][ty + i];
  } else if (bid < 2304 + 16384) {
    const int lane = t & 63;
    const int wid = t >> 6;
    const size_t row = (size_t)(bid - 2304) * 4 + wid;
    const float* p = e + row * 768;
    float x[12];
    float sum = 0.f;
#pragma unroll
    for (int s = 0; s < 3; ++s) {
      f32x4 v = *(const f32x4*)(p + (s * 64 + lane) * 4);
#pragma unroll
      for (int q = 0; q < 4; ++q) { x[s * 4 + q] = v[q]; sum += v[q]; }
    }
#pragma unroll
    for (int d = 1; d < 64; d <<= 1) sum += __shfl_xor(sum, d);
    const float m = sum * (1.f / 768.f);
    float vs = 0.f;
#pragma unroll
    for (int q = 0; q < 12; ++q) { float d = x[q] - m; vs += d * d; }
#pragma unroll
    for (int d = 1; d < 64; d <<= 1) vs += __shfl_xor(vs, d);
    const float rr = rsqrtf(vs * (1.f / 768.f) + 1e-5f);
    __bf16* o = en + row * 768;
#pragma unroll
    for (int s = 0; s < 3; ++s) {
      f32x4 g4 = *(const f32x4*)(gam + (s * 64 + lane) * 4);
      f32x4 b4 = *(const f32x4*)(bet + (s * 64 + lane) * 4);
      bf16x4 pk;
#pragma unroll
      for (int q = 0; q < 4; ++q) pk[q] = (__bf16)((x[s * 4 + q] - m) * rr * g4[q] + b4[q]);
      *(bf16x4*)(o + (s * 64 + lane) * 4) = pk;
    }
  } else {
    constexpr int n4 = 16384 * 768 / 4;
    int i = (bid - 2304 - 16384) * 256 + t;
    for (; i < n4; i += 2048 * 256) {
      f32x4 v = ((const f32x4*)hin)[i];
      bf16x4 o;
#pragma unroll
      for (int q = 0; q < 4; ++q) o[q] = (__bf16)v[q];
      ((bf16x4*)h_bf)[i] = o;
    }
  }
}

// ---------------- 256x256 GEMM body, BK=32, 4-slot ring, 2-phase rotation ----------------
enum { MODE_Q = 0, MODE_KV = 1, MODE_O = 2 };

template <int MODE, int NC>
__device__ __forceinline__ void gemm8_body(
    int wgid, __bf16* As, __bf16* Bs,
    const __bf16* __restrict__ A, const __bf16* __restrict__ WT,
    const float* __restrict__ bias0, const float* __restrict__ bias1,
    const float* __restrict__ eres,
    __bf16* __restrict__ dst0, __bf16* __restrict__ dst1,
    float* __restrict__ outp) {
  const int rowBase = (wgid / NC) * 256;
  const int colBase = (wgid % NC) * 256;
  const int t = threadIdx.x;
  const int lane = t & 63, wid = t >> 6;
  const int wm = wid >> 2, wn = wid & 3;            // 2x4 waves; wave tile 128x64
  const int lr = lane & 15, lg = lane >> 4;         // lg in 0..3
  const int srow = t >> 2;                          // staging row 0..127 per pass
  const int skcol = ((t & 3) ^ (srow & 3)) * 8;     // XOR-swizzled source granule
  const int cg = lg ^ (lr & 3);                     // swizzled read granule
  f32x4 acc[8][4] = {};

  auto stageA = [&](int kt) {
    const int slot = kt & 3;
#pragma unroll
    for (int p = 0; p < 2; ++p) {
      const int rowIn = p * 128 + srow;
      const __bf16* ga;
      if constexpr (MODE == MODE_O) {
        const int r = rowBase + rowIn;
        ga = A + ((((size_t)(r >> 6)) * 12 + (kt >> 1)) << 12) + ((r & 63) << 6) +
             (kt & 1) * 32 + skcol;
      } else {
        ga = A + (size_t)(rowBase + rowIn) * 768 + kt * 32 + skcol;
      }
      load_lds16(ga, &As[slot * 8192 + p * 4096 + t * 8]);
    }
  };
  auto stageB = [&](int kt) {
    const int slot = kt & 3;
#pragma unroll
    for (int p = 0; p < 2; ++p) {
      const int rowIn = p * 128 + srow;
      const __bf16* gb = WT + (size_t)(colBase + rowIn) * 768 + kt * 32 + skcol;
      load_lds16(gb, &Bs[slot * 8192 + p * 4096 + t * 8]);
    }
  };

  // prologue: tiles 0,1,2 in flight (12 loads/thread)
  stageA(0); stageB(0);
  stageA(1); stageB(1);
  stageA(2); stageB(2);

#pragma unroll
  for (int kt = 0; kt < 24; ++kt) {
    const int slot = kt & 3;
    if (kt <= 21) {
      asm volatile("s_waitcnt vmcnt(8)" ::: "memory");
    } else if (kt == 22) {
      asm volatile("s_waitcnt vmcnt(4)" ::: "memory");
    } else {
      asm volatile("s_waitcnt vmcnt(0)" ::: "memory");
    }
    __builtin_amdgcn_sched_barrier(0);
    __builtin_amdgcn_s_barrier();   // tile-kt loads complete; slot (kt+3)&3 free

    // ---- phase 0: it 0..3 ----
    bf16x8 b[4], a0[4];
#pragma unroll
    for (int it = 0; it < 4; ++it)
      a0[it] = *(const bf16x8*)&As[slot * 8192 + (wm * 128 + it * 16 + lr) * 32 + cg * 8];
#pragma unroll
    for (int jt = 0; jt < 4; ++jt)
      b[jt] = *(const bf16x8*)&Bs[slot * 8192 + (wn * 64 + jt * 16 + lr) * 32 + cg * 8];
    if (kt + 3 < 24) stageA(kt + 3);
    asm volatile("s_waitcnt lgkmcnt(0)" ::: "memory");
    __builtin_amdgcn_sched_barrier(0);
    __builtin_amdgcn_s_setprio(1);
#pragma unroll
    for (int it = 0; it < 4; ++it)
#pragma unroll
      for (int jt = 0; jt < 4; ++jt)
        acc[it][jt] = mfma16(a0[it], b[jt], acc[it][jt]);
    __builtin_amdgcn_s_setprio(0);
    __builtin_amdgcn_s_barrier();   // phase rotation

    // ---- phase 1: it 4..7 ----
    bf16x8 a1[4];
#pragma unroll
    for (int it = 0; it < 4; ++it)
      a1[it] = *(const bf16x8*)&As[slot * 8192 + (wm * 128 + (it + 4) * 16 + lr) * 32 + cg * 8];
    if (kt + 3 < 24) stageB(kt + 3);
    asm volatile("s_waitcnt lgkmcnt(0)" ::: "memory");
    __builtin_amdgcn_sched_barrier(0);
    __builtin_amdgcn_s_setprio(1);
#pragma unroll
    for (int it = 0; it < 4; ++it)
#pragma unroll
      for (int jt = 0; jt < 4; ++jt)
        acc[it + 4][jt] = mfma16(a1[it], b[jt], acc[it + 4][jt]);
    __builtin_amdgcn_s_setprio(0);
    // next kt's entry [vmcnt; s_barrier] provides the closing barrier
  }

  // ---- epilogue ----
  const int roww = rowBase + wm * 128;
  const int colw = colBase + wn * 64;
#pragma unroll
  for (int it = 0; it < 8; ++it) {
#pragma unroll
    for (int jt = 0; jt < 4; ++jt) {
      const int c = colw + jt * 16 + lr;
#pragma unroll
      for (int rg = 0; rg < 4; ++rg) {
        const int r = roww + it * 16 + lg * 4 + rg;
        const float val = acc[it][jt][rg];
        if constexpr (MODE == MODE_O) {
          outp[(size_t)r * 768 + c] = val + bias0[c] + eres[(size_t)r * 768 + c];
        } else if constexpr (MODE == MODE_Q) {
          dst0[((((size_t)(r >> 6)) * 12 + (c >> 6)) << 12) + ((r & 63) << 6) + (c & 63)] =
              (__bf16)(val + bias0[c]);
        } else {  // KV: c<768 -> k[bc][h][j][d]; else v transposed [bc][h][d][j]
          if (c < 768) {
            dst0[((((size_t)(r >> 6)) * 12 + (c >> 6)) << 12) + ((r & 63) << 6) + (c & 63)] =
                (__bf16)(val + bias0[c]);
          } else {
            const int c2 = c - 768;
            dst1[((((size_t)(r >> 6)) * 12 + (c2 >> 6)) << 12) + ((c2 & 63) << 6) + (r & 63)] =
                (__bf16)(val + bias1[c2]);
          }
        }
      }
    }
  }
}

// merged Q + KV GEMM: blocks [0,768) = Q (256-row x 256-col tiles of en@WqT);
// blocks [768, 1152) = KV (h_bf @ WkvT).  Independent outputs; single grid so
// CUs flow from Q's ragged tail straight into KV (no inter-dispatch sync).
__global__ __launch_bounds__(512) void gemm_qkv_kernel(
    const __bf16* __restrict__ en, const __bf16* __restrict__ WqT,
    const float* __restrict__ bq, __bf16* __restrict__ q_ws,
    const __bf16* __restrict__ h_bf, const __bf16* __restrict__ WkvT,
    const float* __restrict__ bk, const float* __restrict__ bv,
    __bf16* __restrict__ k_ws, __bf16* __restrict__ v_ws) {
  __shared__ __bf16 As[4 * 8192];
  __shared__ __bf16 Bs[4 * 8192];
  const int bid = blockIdx.x;
  if (bid < 768) {
    gemm8_body<MODE_Q, 3>(xcd_swz<768>(bid), As, Bs, en, WqT, bq, nullptr,
                          nullptr, q_ws, nullptr, nullptr);
  } else {
    gemm8_body<MODE_KV, 6>(xcd_swz<384>(bid - 768), As, Bs, h_bf, WkvT, bk, bv,
                           nullptr, k_ws, v_ws, nullptr);
  }
}

__global__ __launch_bounds__(512) void gemm_o_kernel(
    const __bf16* __restrict__ o_ws, const __bf16* __restrict__ WoT,
    const float* __restrict__ bo, const float* __restrict__ e,
    float* __restrict__ outp) {
  __shared__ __bf16 As[4 * 8192];
  __shared__ __bf16 Bs[4 * 8192];
  gemm8_body<MODE_O, 3>(xcd_swz<768>(blockIdx.x), As, Bs, o_ws, WoT, bo,
                        nullptr, e, nullptr, nullptr, outp);
}

// ---------------- attention: block = (bc,h), 4 waves = 4 n's sharing K/V in LDS ----------------
__global__ __launch_bounds__(256) void attn_kernel(
    const __bf16* __restrict__ q, const __bf16* __restrict__ k,
    const __bf16* __restrict__ v, __bf16* __restrict__ o) {
  const int bh = blockIdx.x;           // bc*12 + h
  const int h = bh % 12;
  const int bc = bh / 12;
  const int t = threadIdx.x;
  const int wid = t >> 6, lane = t & 63;
  const int lr = lane & 15, lg = lane >> 4;
  __shared__ __bf16 kL[64][72];        // pad-72: b128 row-reads are 2-way (free)
  __shared__ __bf16 vL[64][72];        // v stored transposed [d][j]
  __shared__ __bf16 P[4][64][72];      // per-wave P slab

  {
    const __bf16* kp = k + ((size_t)bh << 12);
    const __bf16* vp = v + ((size_t)bh << 12);
    const int row = t >> 2, col = (t & 3) * 16;
    *(bf16x8*)&kL[row][col]     = *(const bf16x8*)(kp + row * 64 + col);
    *(bf16x8*)&kL[row][col + 8] = *(const bf16x8*)(kp + row * 64 + col + 8);
    *(bf16x8*)&vL[row][col]     = *(const bf16x8*)(vp + row * 64 + col);
    *(bf16x8*)&vL[row][col + 8] = *(const bf16x8*)(vp + row * 64 + col + 8);
  }
  const __bf16* qp = q + (((size_t)(bc * 4 + wid) * 12 + h) << 12);
  __bf16* op = o + (((size_t)(bc * 4 + wid) * 12 + h) << 12);
  bf16x8 qf[4][2];
#pragma unroll
  for (int it = 0; it < 4; ++it)
#pragma unroll
    for (int kc = 0; kc < 2; ++kc)
      qf[it][kc] = *(const bf16x8*)(qp + (it * 16 + lr) * 64 + kc * 32 + lg * 8);
  __syncthreads();

  // S^T = k @ q^T : lane holds S[i = it*16+lr][j = jt*16+lg*4+rg]
  f32x4 s[4][4] = {};
#pragma unroll
  for (int kc = 0; kc < 2; ++kc) {
    bf16x8 kf[4];
#pragma unroll
    for (int jt = 0; jt < 4; ++jt)
      kf[jt] = *(const bf16x8*)&kL[jt * 16 + lr][kc * 32 + lg * 8];
#pragma unroll
    for (int jt = 0; jt < 4; ++jt)
#pragma unroll
      for (int it = 0; it < 4; ++it)
        s[jt][it] = mfma16(kf[jt], qf[it][kc], s[jt][it]);
  }

  float recip[4];
#pragma unroll
  for (int it = 0; it < 4; ++it) {
    float m = -1e30f;
#pragma unroll
    for (int jt = 0; jt < 4; ++jt)
#pragma unroll
      for (int rg = 0; rg < 4; ++rg) m = fmaxf(m, s[jt][it][rg]);
    m = fmaxf(m, __shfl_xor(m, 16));
    m = fmaxf(m, __shfl_xor(m, 32));
    float sum = 0.f;
#pragma unroll
    for (int jt = 0; jt < 4; ++jt) {
      bf16x4 pk;
#pragma unroll
      for (int rg = 0; rg < 4; ++rg) {
        float p = __expf((s[jt][it][rg] - m) * 0.125f);
        sum += p;
        pk[rg] = (__bf16)p;
      }
      *(bf16x4*)&P[wid][it * 16 + lr][jt * 16 + lg * 4] = pk;
    }
    sum += __shfl_xor(sum, 16);
    sum += __shfl_xor(sum, 32);
    recip[it] = 1.f / sum;
  }
  // P is per-wave: no block barrier needed

  // o^T = vT @ P^T
  f32x4 oacc[4][4] = {};
#pragma unroll
  for (int kc = 0; kc < 2; ++kc) {
    bf16x8 vf[4], pf[4];
#pragma unroll
    for (int dt = 0; dt < 4; ++dt)
      vf[dt] = *(const bf16x8*)&vL[dt * 16 + lr][kc * 32 + lg * 8];
#pragma unroll
    for (int it = 0; it < 4; ++it)
      pf[it] = *(const bf16x8*)&P[wid][it * 16 + lr][kc * 32 + lg * 8];
#pragma unroll
    for (int dt = 0; dt < 4; ++dt)
#pragma unroll
      for (int it = 0; it < 4; ++it)
        oacc[dt][it] = mfma16(vf[dt], pf[it], oacc[dt][it]);
  }
#pragma unroll
  for (int it = 0; it < 4; ++it) {
    const float rc = recip[it];
#pragma unroll
    for (int dt = 0; dt < 4; ++dt) {
      bf16x4 pk;
#pragma unroll
      for (int rg = 0; rg < 4; ++rg) pk[rg] = (__bf16)(oacc[dt][it][rg] * rc);
      *(bf16x4*)(op + (size_t)(it * 16 + lr) * 64 + dt * 16 + lg * 4) = pk;
    }
  }
}

extern "C" void kernel_launch(void* const* d_in, const int* in_sizes, int n_in,
                              void* d_out, int out_size, void* d_ws, size_t ws_size,
                              hipStream_t stream) {
  const float* e  = (const float*)d_in[0];
  const float* h  = (const float*)d_in[1];
  const float* Wq = (const float*)d_in[2];
  const float* bq = (const float*)d_in[3];
  const float* Wk = (const float*)d_in[4];
  const float* bk = (const float*)d_in[5];
  const float* Wv = (const float*)d_in[6];
  const float* bv = (const float*)d_in[7];
  const float* Wo = (const float*)d_in[8];
  const float* bo = (const float*)d_in[9];
  const float* g  = (const float*)d_in[10];
  const float* b  = (const float*)d_in[11];
  float* outp = (float*)d_out;
  char* ws = (char*)d_ws;

  __bf16* WqT  = (__bf16*)(ws);                    // 1,179,648
  __bf16* WkvT = (__bf16*)(ws + 1179648);          // 2,359,296
  __bf16* WoT  = (__bf16*)(ws + 3538944);          // 1,179,648
  __bf16* en   = (__bf16*)(ws + 4718592);          // 100,663,296 (ln -> Q-GEMM)
  __bf16* q_ws = (__bf16*)(ws + 105381888);        // 100,663,296 (o in-place)
  __bf16* h_bf = (__bf16*)(ws + 206045184);        // 25,165,824
  __bf16* k_ws = (__bf16*)(ws + 231211008);        // 25,165,824
  __bf16* v_ws = (__bf16*)(ws + 256376832);        // 25,165,824 (ws >= 282 MB)

  prep_ln_cast_kernel<<<2304 + 16384 + 2048, 256, 0, stream>>>(
      Wq, Wk, Wv, Wo, WqT, WkvT, WoT, e, g, b, en, h, h_bf);
  gemm_qkv_kernel<<<1152, 512, 0, stream>>>(
      en, WqT, bq, q_ws, h_bf, WkvT, bk, bv, k_ws, v_ws);
  attn_kernel<<<3072, 256, 0, stream>>>(q_ws, k_ws, v_ws, q_ws);
  gemm_o_kernel<<<768, 512, 0, stream>>>(q_ws, WoT, bo, e, outp);
}